// Round 7
// baseline (8748.448 us; speedup 1.0000x reference)
//
#include <hip/hip_runtime.h>
#include <cstddef>

// LSTM: N=64, T=512, D=512, H=512.
// gates[t] = [x_t | h_{t-1}] @ [Wx; Wh] + b  (K=1024, fp16 MFMA 32x32x16)
// SINGLE-XCD persistent scan: 256 WGs launched; the 32 WGs resident on
// blockIdx-0's XCD elect themselves (s_getreg XCC_ID + atomic ticket) and
// run the whole recurrence; others exit. All h/flag exchange stays within
// one XCD (agent-scope atomics; correct even if election degrades to
// cross-XCD). Each WG owns 64 gate cols (16 h-units x 4 gates interleaved),
// weights LDS-resident (128 KB, fragment-linear, conflict-free), 2x2 waves
// of 32x32 output tiles. Sync = R2-proven: ack(vmcnt0) -> flag -> single
// poller + __syncthreads broadcast. Cell = R5-proven shfl butterfly.

typedef _Float16 half8 __attribute__((ext_vector_type(8)));
typedef float f32x16 __attribute__((ext_vector_type(16)));
typedef unsigned long long u64x2 __attribute__((ext_vector_type(2)));

#define NBATCH 64
#define TSTEPS 512
#define DIN    512
#define HID    512
#define NCOL   2048
#define HSLOT  (NBATCH * HID)   // fp16 elements per ping-pong slot

__device__ __forceinline__ float fast_sigmoid(float x) {
  return 1.0f / (1.0f + __expf(-x));
}
__device__ __forceinline__ float fast_tanh(float x) {
  return 1.0f - 2.0f / (__expf(2.0f * x) + 1.0f);
}

// one-time per launch: x -> fp16; h0 -> slot 0; reset flags + election ctl
__global__ void lstm_prep(const float* __restrict__ x, const float* __restrict__ h0,
                          _Float16* __restrict__ xb, _Float16* __restrict__ hbuf,
                          unsigned* __restrict__ flags, unsigned* __restrict__ ctl)
{
  size_t gid = (size_t)blockIdx.x * blockDim.x + threadIdx.x;
  size_t stride = (size_t)gridDim.x * blockDim.x;
  const size_t NX = (size_t)NBATCH * TSTEPS * DIN;
  for (size_t i = gid * 4; i < NX; i += stride * 4) {
    float4 v = *(const float4*)(x + i);
    xb[i + 0] = (_Float16)v.x;
    xb[i + 1] = (_Float16)v.y;
    xb[i + 2] = (_Float16)v.z;
    xb[i + 3] = (_Float16)v.w;
  }
  for (size_t i = gid; i < (size_t)HSLOT; i += stride)
    hbuf[i] = (_Float16)h0[i];
  if (gid < 32) flags[gid] = 0u;
  if (gid == 32) { ctl[0] = 0u; ctl[1] = 0u; }
}

__global__ __launch_bounds__(256, 1) void lstm_scan(
    const _Float16* __restrict__ xb,   // [N][T][D] fp16
    const float* __restrict__ Wx,      // [D][4H]
    const float* __restrict__ Wh,      // [H][4H]
    const float* __restrict__ bias,    // [4H]
    _Float16* __restrict__ hbuf,       // [2][N][H] fp16 ping-pong
    float* __restrict__ out,           // [N][T][H] fp32
    unsigned* __restrict__ flags,      // [32] per-WG step counters
    unsigned* __restrict__ ctl)        // [0]=chosen xcd|0x100, [1]=rank ctr
{
  // fragment-linear weights for mfma_f32_32x32x16_f16:
  // WF[cg*64+ks][lane] = 16B B-fragment (cols cg*32+(lane&31),
  // k = ks*16 + (lane>>5)*8 + j).  128 KB.
  __shared__ half8 WF[128][64];
  __shared__ int s_rank;

  const int tid = threadIdx.x;

  // ---- election: the 32 WGs on blockIdx-0's XCD run the scan ----
  if (tid == 0) {
    int xcc = __builtin_amdgcn_s_getreg(63508) & 0xF;  // hwreg(XCC_ID,0,32)
    if (blockIdx.x == 0)
      __hip_atomic_store(&ctl[0], 0x100u | (unsigned)xcc,
                         __ATOMIC_RELAXED, __HIP_MEMORY_SCOPE_AGENT);
    unsigned ch;
    while (!(ch = __hip_atomic_load(&ctl[0], __ATOMIC_RELAXED,
                                    __HIP_MEMORY_SCOPE_AGENT)))
      __builtin_amdgcn_s_sleep(8);
    int r = -1;
    if ((int)(ch & 0xFu) == xcc)
      r = (int)__hip_atomic_fetch_add(&ctl[1], 1u, __ATOMIC_RELAXED,
                                      __HIP_MEMORY_SCOPE_AGENT);
    s_rank = r;
  }
  __syncthreads();
  const int rank = s_rank;
  if (rank < 0 || rank >= 32) return;   // uniform per WG

  // ---- stage weight slice fp32 -> fp16 LDS (fragment-linear) ----
  // local col c = hu*4 + g (hu 0..15, g 0..3); source col = g*512+rank*16+hu
  {
    const int hu = tid & 15, g = (tid >> 4) & 3, kq = tid >> 6;
    const int c = hu * 4 + g;
    const size_t gc = (size_t)g * 512 + rank * 16 + hu;
    _Float16* wf = (_Float16*)WF;
    for (int k = kq; k < 1024; k += 4) {
      float w = (k < 512) ? Wx[(size_t)k * NCOL + gc]
                          : Wh[(size_t)(k - 512) * NCOL + gc];
      int addr = ((c >> 5) * 64 + (k >> 4)) * 512 +
                 (((k >> 3) & 1) * 32 + (c & 31)) * 8 + (k & 7);
      wf[addr] = (_Float16)w;
    }
  }
  __syncthreads();

  // ---- wave identity: 2x2 grid of 32x32 tiles over 64 rows x 64 cols ----
  const int lane = tid & 63;
  const int wave = tid >> 6;
  const int rg = wave >> 1, cg = wave & 1;
  const int l31 = lane & 31, hi = lane >> 5;
  const int n_A = rg * 32 + l31;        // batch row of this lane's A-frags
  const int g = l31 & 3;                // gate of this lane's output col
  const int hu_loc = l31 >> 2;          // 0..7 within cg-half
  const int unit = rank * 16 + cg * 8 + hu_loc;   // global hidden unit
  const float bias_l = bias[(size_t)g * 512 + unit];

  float cst[16];
#pragma unroll
  for (int r = 0; r < 16; ++r) cst[r] = 0.f;

  const unsigned long long* flag64 = (const unsigned long long*)flags;

  for (int t = 0; t < TSTEPS; ++t) {
    // ---- x A-frags: plain cached loads, issued BEFORE the poll ----
    half8 xa[32];
    const _Float16* xrow = xb + ((size_t)n_A * TSTEPS + t) * DIN + hi * 8;
#pragma unroll
    for (int ks = 0; ks < 32; ++ks)
      xa[ks] = *(const half8*)(xrow + ks * 16);

    // ---- discovery: single poller (16 lanes cover 32 flags), broadcast ----
    if (t) {
      if (tid < 16) {
        for (;;) {
          unsigned long long v = __hip_atomic_load(
              flag64 + tid, __ATOMIC_RELAXED, __HIP_MEMORY_SCOPE_AGENT);
          bool ok = ((unsigned)v >= (unsigned)t) &&
                    ((unsigned)(v >> 32) >= (unsigned)t);
          if (__all(ok)) break;
          __builtin_amdgcn_s_sleep(1);
        }
      }
      __syncthreads();
    }

    // ---- h A-frags: 64 compiler-tracked u64 agent loads ----
    const unsigned long long* hrow64 = (const unsigned long long*)
        (hbuf + (size_t)(t & 1) * HSLOT + (size_t)n_A * HID);
    unsigned long long hl[32][2];
#pragma unroll
    for (int s = 0; s < 32; ++s) {
      hl[s][0] = __hip_atomic_load(hrow64 + s * 4 + hi * 2,
                                   __ATOMIC_RELAXED, __HIP_MEMORY_SCOPE_AGENT);
      hl[s][1] = __hip_atomic_load(hrow64 + s * 4 + hi * 2 + 1,
                                   __ATOMIC_RELAXED, __HIP_MEMORY_SCOPE_AGENT);
    }

    // ---- GEMM: x phase (overlaps h flight), then h phase ----
    f32x16 ae = {0.f,0.f,0.f,0.f,0.f,0.f,0.f,0.f,0.f,0.f,0.f,0.f,0.f,0.f,0.f,0.f};
    f32x16 ao = ae;
#pragma unroll
    for (int ks = 0; ks < 32; ks += 2) {
      ae = __builtin_amdgcn_mfma_f32_32x32x16_f16(xa[ks],     WF[cg*64+ks][lane],   ae, 0, 0, 0);
      ao = __builtin_amdgcn_mfma_f32_32x32x16_f16(xa[ks + 1], WF[cg*64+ks+1][lane], ao, 0, 0, 0);
    }
#pragma unroll
    for (int s = 0; s < 32; s += 2) {
      u64x2 d0 = {hl[s][0],     hl[s][1]};
      u64x2 d1 = {hl[s + 1][0], hl[s + 1][1]};
      ae = __builtin_amdgcn_mfma_f32_32x32x16_f16(__builtin_bit_cast(half8, d0),
                                                  WF[cg*64+32+s][lane],   ae, 0, 0, 0);
      ao = __builtin_amdgcn_mfma_f32_32x32x16_f16(__builtin_bit_cast(half8, d1),
                                                  WF[cg*64+33+s][lane], ao, 0, 0, 0);
    }
    f32x16 acc = ae + ao;

    // ---- cell: shfl butterfly (masks 1,2 within the 4-lane gate group) ----
    // D layout: col = lane&31, row = (r&3) + 8*(r>>2) + 4*hi  (m74/m101)
    float hv[16];
#pragma unroll
    for (int r = 0; r < 16; ++r) {
      float av = acc[r] + bias_l;
      float v1 = __shfl_xor(av, 1);
      float alo = (g & 1) ? v1 : av;     // gate (g&2)+0
      float ahi = (g & 1) ? av : v1;     // gate (g&2)+1
      float blo = __shfl_xor(alo, 2);
      float bhi = __shfl_xor(ahi, 2);
      float iv = (g & 2) ? blo : alo;    // i
      float fv = (g & 2) ? bhi : ahi;    // f
      float ov = (g & 2) ? alo : blo;    // o
      float gv = (g & 2) ? ahi : bhi;    // g
      float ig = fast_sigmoid(iv);
      float fg = fast_sigmoid(fv);
      float og = fast_sigmoid(ov);
      float gg = fast_tanh(gv);
      cst[r] = fg * cst[r] + ig * gg;
      hv[r] = og * fast_tanh(cst[r]);
    }

    // ---- publish h (paired u32, agent store) + out (plain fp32) ----
    _Float16* hslot = hbuf + (size_t)((t + 1) & 1) * HSLOT;
    const bool hwriter = ((lane & 7) == 0);   // g==0 && hu even
    const bool owriter = ((lane & 3) == 0);   // g==0
#pragma unroll
    for (int r = 0; r < 16; ++r) {
      int row = rg * 32 + (r & 3) + 8 * (r >> 2) + 4 * hi;
      float hp = __shfl_xor(hv[r], 4);        // partner hu^1, same gate
      if (hwriter) {
        _Float16 lo16 = (_Float16)hv[r], hi16 = (_Float16)hp;
        unsigned packed = (unsigned)__builtin_bit_cast(unsigned short, lo16) |
                          ((unsigned)__builtin_bit_cast(unsigned short, hi16) << 16);
        __hip_atomic_store((unsigned*)(hslot + (size_t)row * HID + unit), packed,
                           __ATOMIC_RELAXED, __HIP_MEMORY_SCOPE_AGENT);
      }
      if (owriter)
        out[((size_t)row * TSTEPS + t) * HID + unit] = hv[r];
    }

    // ---- ack + arrive ----
    asm volatile("s_waitcnt vmcnt(0)" ::: "memory");
    __syncthreads();
    if (tid == 0)
      __hip_atomic_store(&flags[rank], (unsigned)(t + 1),
                         __ATOMIC_RELAXED, __HIP_MEMORY_SCOPE_AGENT);
  }
}

extern "C" void kernel_launch(void* const* d_in, const int* in_sizes, int n_in,
                              void* d_out, int out_size, void* d_ws, size_t ws_size,
                              hipStream_t stream) {
  const float* x  = (const float*)d_in[0];
  const float* h0 = (const float*)d_in[1];
  const float* Wx = (const float*)d_in[2];
  const float* Wh = (const float*)d_in[3];
  const float* b  = (const float*)d_in[4];
  float* out = (float*)d_out;

  char* ws = (char*)d_ws;
  _Float16* xb    = (_Float16*)ws;                           // 33,554,432 B
  _Float16* hbuf  = (_Float16*)(ws + 33554432);              //    131,072 B
  unsigned* flags = (unsigned*)(ws + 33554432 + 131072);     //        128 B
  unsigned* ctl   = (unsigned*)(ws + 33554432 + 131072 + 128); //       8 B

  lstm_prep<<<dim3(2048), dim3(256), 0, stream>>>(x, h0, xb, hbuf, flags, ctl);
  lstm_scan<<<dim3(256), dim3(256), 0, stream>>>(xb, Wx, Wh, b, hbuf, out, flags, ctl);
}

// Round 8
// 3664.114 us; speedup vs baseline: 2.3876x; 2.3876x over previous
//
#include <hip/hip_runtime.h>
#include <cstddef>

// LSTM: N=64, T=512, D=512, H=512.
// gates[t] = [x_t | h_{t-1}] @ [Wx; Wh] + b  (K=1024, fp16 MFMA, fp32 accum)
// Persistent scan: 128 WGs x 256 thr, each WG owns 4 hidden units (16 gate
// cols). Consolidation of proven components:
//   R2: WG-level flags, single-poll-wave + __syncthreads broadcast,
//       sc1 write-through h, vmcnt(0) ack before flag publish
//   R3: fragment-linear LDS weights (conflict-free ds_read_b128)
//   R5/R6: in-register shfl-butterfly LSTM cell (no LDS epilogue),
//       compiler-tracked u64 agent h-loads (no inline-asm load hazard)

typedef _Float16 half8 __attribute__((ext_vector_type(8)));
typedef float f32x4 __attribute__((ext_vector_type(4)));
typedef unsigned long long u64x2 __attribute__((ext_vector_type(2)));

#define NBATCH 64
#define TSTEPS 512
#define DIN    512
#define HID    512
#define NCOL   2048
#define SCAN_WGS 128
#define HSLOT  (NBATCH * HID)   // fp16 elements per ping-pong slot

__device__ __forceinline__ float fast_sigmoid(float x) {
  return 1.0f / (1.0f + __expf(-x));
}
__device__ __forceinline__ float fast_tanh(float x) {
  return 1.0f - 2.0f / (__expf(2.0f * x) + 1.0f);
}

// one-time per launch: x -> fp16; h0 -> slot 0; reset 128 WG flags
__global__ void lstm_prep(const float* __restrict__ x, const float* __restrict__ h0,
                          _Float16* __restrict__ xb, _Float16* __restrict__ hbuf,
                          unsigned* __restrict__ flags)
{
  size_t gid = (size_t)blockIdx.x * blockDim.x + threadIdx.x;
  size_t stride = (size_t)gridDim.x * blockDim.x;
  const size_t NX = (size_t)NBATCH * TSTEPS * DIN;
  for (size_t i = gid * 4; i < NX; i += stride * 4) {
    float4 v = *(const float4*)(x + i);
    xb[i + 0] = (_Float16)v.x;
    xb[i + 1] = (_Float16)v.y;
    xb[i + 2] = (_Float16)v.z;
    xb[i + 3] = (_Float16)v.w;
  }
  for (size_t i = gid; i < (size_t)HSLOT; i += stride)
    hbuf[i] = (_Float16)h0[i];
  if (gid < SCAN_WGS) flags[gid] = 0u;
}

__global__ __launch_bounds__(256, 1) void lstm_scan(
    const _Float16* __restrict__ xb,   // [N][T][D] fp16
    const float* __restrict__ Wx,      // [D][4H]
    const float* __restrict__ Wh,      // [H][4H]
    const float* __restrict__ bias,    // [4H]
    _Float16* __restrict__ hbuf,       // [2][N][H] fp16 ping-pong
    float* __restrict__ out,           // [N][T][H] fp32
    unsigned* __restrict__ flags)      // [128] per-WG step counters
{
  // fragment-linear weights: WF[ks][lane] = 16B B-fragment for K-slice ks
  __shared__ half8 WxF[16][64];        // 16 KB
  __shared__ half8 WhF[16][64];        // 16 KB

  const int wg   = blockIdx.x;         // owns hidden units wg*4..wg*4+3
  const int tid  = threadIdx.x;
  const int lane = tid & 63;
  const int wave = tid >> 6;           // m-slice: batch rows wave*16..+15

  // ---- one-time: stage weight slices fp32->fp16 into LDS (fragment order)
  {
    const int gate = tid & 3;
    const int k0   = tid >> 2;         // 0..63
    _Float16* wx = (_Float16*)WxF;
    _Float16* wh = (_Float16*)WhF;
    for (int pass = 0; pass < 8; ++pass) {
      int k = k0 + pass * 64;
      float4 vx = *(const float4*)(Wx + (size_t)k * NCOL + gate * 512 + wg * 4);
      float4 vh = *(const float4*)(Wh + (size_t)k * NCOL + gate * 512 + wg * 4);
      int base = (k >> 5) * 512 + (((k >> 3) & 3) * 16 + gate * 4) * 8 + (k & 7);
      wx[base + 0 * 8] = (_Float16)vx.x;
      wx[base + 1 * 8] = (_Float16)vx.y;
      wx[base + 2 * 8] = (_Float16)vx.z;
      wx[base + 3 * 8] = (_Float16)vx.w;
      wh[base + 0 * 8] = (_Float16)vh.x;
      wh[base + 1 * 8] = (_Float16)vh.y;
      wh[base + 2 * 8] = (_Float16)vh.z;
      wh[base + 3 * 8] = (_Float16)vh.w;
    }
  }
  __syncthreads();

  // MFMA 16x16x32 fragment indices (A: row=lane&15, k=(lane>>4)*8+j;
  //  D: col=lane&15, row=(lane>>4)*4+j)
  const int fr = lane & 15;
  const int q  = lane >> 4;
  const int fk = q * 8;
  const int mrow = wave * 16 + fr;     // batch row of this lane's A-fragment

  // per-lane bias for gate column fr: gate g=fr>>2, hidden hj=fr&3
  const float bias_fr = bias[(fr >> 2) * 512 + wg * 4 + (fr & 3)];

  // writer identity: lane publishes cell (nw, colw), j_w = fr>>2
  const int jw   = fr >> 2;
  const int nw   = wave * 16 + q * 4 + jw;
  const int colw = wg * 4 + (fr & 3);

  // cell state for rows q*4+j (j=0..3), hidden unit fr&3 (replicated over g)
  float c0 = 0.f, c1 = 0.f, c2 = 0.f, c3 = 0.f;

  // preload x fragments for t=0
  half8 xa[16];
#pragma unroll
  for (int ks = 0; ks < 16; ++ks)
    xa[ks] = *(const half8*)(xb + ((size_t)mrow * TSTEPS + 0) * DIN + ks * 32 + fk);

  const unsigned long long* flag64 = (const unsigned long long*)flags;

  for (int t = 0; t < TSTEPS; ++t) {
    // ---- discovery: wave 0 polls all 128 WG flags, broadcast via barrier
    if (t) {
      if (tid < 64) {
        for (;;) {
          unsigned long long v = __hip_atomic_load(
              flag64 + tid, __ATOMIC_RELAXED, __HIP_MEMORY_SCOPE_AGENT);
          bool pok = ((unsigned)v >= (unsigned)t) &&
                     ((unsigned)(v >> 32) >= (unsigned)t);
          if (__all(pok)) break;
          __builtin_amdgcn_s_sleep(1);
        }
      }
      __syncthreads();
    }

    // ---- issue h loads: 16 frags x 2 u64 (compiler-tracked dwordx2 sc1) ----
    const unsigned long long* hrow = (const unsigned long long*)
        (hbuf + (size_t)(t & 1) * HSLOT + (size_t)mrow * HID);
    unsigned long long hl[16][2];
#pragma unroll
    for (int ks = 0; ks < 16; ++ks) {
      hl[ks][0] = __hip_atomic_load(hrow + ks * 8 + q * 2,
                                    __ATOMIC_RELAXED, __HIP_MEMORY_SCOPE_AGENT);
      hl[ks][1] = __hip_atomic_load(hrow + ks * 8 + q * 2 + 1,
                                    __ATOMIC_RELAXED, __HIP_MEMORY_SCOPE_AGENT);
    }

    // ---- x-MFMA phase (independent of h loads; overlaps their flight) ----
    f32x4 a0 = {0.f, 0.f, 0.f, 0.f};
    f32x4 a1 = {0.f, 0.f, 0.f, 0.f};
    f32x4 a2 = {0.f, 0.f, 0.f, 0.f};
    f32x4 a3 = {0.f, 0.f, 0.f, 0.f};
#pragma unroll
    for (int ks = 0; ks < 16; ks += 4) {
      a0 = __builtin_amdgcn_mfma_f32_16x16x32_f16(xa[ks],     WxF[ks][lane],     a0, 0, 0, 0);
      a1 = __builtin_amdgcn_mfma_f32_16x16x32_f16(xa[ks + 1], WxF[ks + 1][lane], a1, 0, 0, 0);
      a2 = __builtin_amdgcn_mfma_f32_16x16x32_f16(xa[ks + 2], WxF[ks + 2][lane], a2, 0, 0, 0);
      a3 = __builtin_amdgcn_mfma_f32_16x16x32_f16(xa[ks + 3], WxF[ks + 3][lane], a3, 0, 0, 0);
    }

    // ---- h-MFMA phase (compiler inserts counted waits on hl) ----
#pragma unroll
    for (int ks = 0; ks < 16; ks += 4) {
      u64x2 d0 = {hl[ks][0],     hl[ks][1]};
      u64x2 d1 = {hl[ks + 1][0], hl[ks + 1][1]};
      u64x2 d2 = {hl[ks + 2][0], hl[ks + 2][1]};
      u64x2 d3 = {hl[ks + 3][0], hl[ks + 3][1]};
      a0 = __builtin_amdgcn_mfma_f32_16x16x32_f16(__builtin_bit_cast(half8, d0), WhF[ks][lane],     a0, 0, 0, 0);
      a1 = __builtin_amdgcn_mfma_f32_16x16x32_f16(__builtin_bit_cast(half8, d1), WhF[ks + 1][lane], a1, 0, 0, 0);
      a2 = __builtin_amdgcn_mfma_f32_16x16x32_f16(__builtin_bit_cast(half8, d2), WhF[ks + 2][lane], a2, 0, 0, 0);
      a3 = __builtin_amdgcn_mfma_f32_16x16x32_f16(__builtin_bit_cast(half8, d3), WhF[ks + 3][lane], a3, 0, 0, 0);
    }
    f32x4 acc = (a0 + a1) + (a2 + a3);

    // ---- in-register LSTM cell (gates exchanged via shfl_xor 4/8) ----
    float h0v, h1v, h2v, h3v;
#define LSTM_CELL(J, CJ, HJ)                                                  \
    {                                                                         \
      float av = acc[J] + bias_fr;                                            \
      float v4 = __shfl_xor(av, 4);                                           \
      float alo = (fr & 4) ? v4 : av;                                         \
      float ahi = (fr & 4) ? av : v4;                                         \
      float blo = __shfl_xor(alo, 8);                                         \
      float bhi = __shfl_xor(ahi, 8);                                         \
      float iv = (fr & 8) ? blo : alo;   /* gate 0: i */                      \
      float fv = (fr & 8) ? bhi : ahi;   /* gate 1: f */                      \
      float ov = (fr & 8) ? alo : blo;   /* gate 2: o */                      \
      float gv = (fr & 8) ? ahi : bhi;   /* gate 3: g */                      \
      float ig = fast_sigmoid(iv);                                            \
      float fg = fast_sigmoid(fv);                                            \
      float og = fast_sigmoid(ov);                                            \
      float gg = fast_tanh(gv);                                               \
      CJ = fg * CJ + ig * gg;                                                 \
      HJ = og * fast_tanh(CJ);                                                \
    }
    LSTM_CELL(0, c0, h0v)
    LSTM_CELL(1, c1, h1v)
    LSTM_CELL(2, c2, h2v)
    LSTM_CELL(3, c3, h3v)
#undef LSTM_CELL

    // writer value: j == jw (static-select, keeps arrays out of scratch)
    float hsel = (jw == 0) ? h0v : (jw == 1) ? h1v : (jw == 2) ? h2v : h3v;

    // ---- publish h (paired u32, agent store) + out (plain fp32) ----
    {
      float hpart = __shfl_xor(hsel, 1);
      if ((fr & 1) == 0) {
        _Float16 lo = (_Float16)hsel, hi = (_Float16)hpart;
        unsigned packed = (unsigned)__builtin_bit_cast(unsigned short, lo) |
                          ((unsigned)__builtin_bit_cast(unsigned short, hi) << 16);
        unsigned* hdst = (unsigned*)(hbuf + (size_t)((t + 1) & 1) * HSLOT +
                                     (size_t)nw * HID + colw);
        __hip_atomic_store(hdst, packed, __ATOMIC_RELAXED, __HIP_MEMORY_SCOPE_AGENT);
      }
    }
    out[((size_t)nw * TSTEPS + t) * HID + colw] = hsel;

    // ---- ack: all waves' h stores at coherence point, then WG flag ----
    asm volatile("s_waitcnt vmcnt(0)" ::: "memory");
    __syncthreads();
    if (tid == 0)
      __hip_atomic_store(&flags[wg], (unsigned)(t + 1),
                         __ATOMIC_RELAXED, __HIP_MEMORY_SCOPE_AGENT);

    // ---- prefetch x for t+1 (lands during next poll window) ----
    if (t + 1 < TSTEPS) {
#pragma unroll
      for (int ks = 0; ks < 16; ++ks)
        xa[ks] = *(const half8*)(xb + ((size_t)mrow * TSTEPS + (t + 1)) * DIN + ks * 32 + fk);
    }
  }
}

extern "C" void kernel_launch(void* const* d_in, const int* in_sizes, int n_in,
                              void* d_out, int out_size, void* d_ws, size_t ws_size,
                              hipStream_t stream) {
  const float* x  = (const float*)d_in[0];
  const float* h0 = (const float*)d_in[1];
  const float* Wx = (const float*)d_in[2];
  const float* Wh = (const float*)d_in[3];
  const float* b  = (const float*)d_in[4];
  float* out = (float*)d_out;

  char* ws = (char*)d_ws;
  _Float16* xb    = (_Float16*)ws;                           // 33,554,432 B
  _Float16* hbuf  = (_Float16*)(ws + 33554432);              //    262,144 B
  unsigned* flags = (unsigned*)(ws + 33554432 + 262144);     //        512 B

  lstm_prep<<<dim3(2048), dim3(256), 0, stream>>>(x, h0, xb, hbuf, flags);
  lstm_scan<<<dim3(SCAN_WGS), dim3(256), 0, stream>>>(xb, Wx, Wh, b, hbuf, out, flags);
}

// Round 9
// 3009.236 us; speedup vs baseline: 2.9072x; 1.2176x over previous
//
#include <hip/hip_runtime.h>
#include <cstddef>

// LSTM: N=64, T=512, D=512, H=512.
// gates[t] = [x_t | h_{t-1}] @ [Wx; Wh] + b  (K=1024, fp16 MFMA, fp32 accum)
// Persistent scan: 128 WGs x 256 thr, each WG owns 4 hidden units (16 gate
// cols). R2 sync skeleton (WG flags, single-poll-wave + syncthreads
// broadcast, sc1 write-through h, vmcnt(0) ack) + R3 fragment-linear LDS
// weights + R5/R6 in-register shfl cell. h transport: ONE inline-asm block
// containing 16 pipelined global_load_dwordx4 sc1 (base + offset:imm) AND
// the s_waitcnt vmcnt(0) -- no compiler-inserted copy/spill can slip
// between load and wait (R4 hazard structurally impossible), and all 16
// loads share a single latency exposure (R8's load-sinking fixed).

typedef _Float16 half8 __attribute__((ext_vector_type(8)));
typedef float f32x4 __attribute__((ext_vector_type(4)));
typedef unsigned u32x4 __attribute__((ext_vector_type(4)));

#define NBATCH 64
#define TSTEPS 512
#define DIN    512
#define HID    512
#define NCOL   2048
#define SCAN_WGS 128
#define HSLOT  (NBATCH * HID)   // fp16 elements per ping-pong slot

__device__ __forceinline__ float fast_sigmoid(float x) {
  return 1.0f / (1.0f + __expf(-x));
}
__device__ __forceinline__ float fast_tanh(float x) {
  return 1.0f - 2.0f / (__expf(2.0f * x) + 1.0f);
}

// one-time per launch: x -> fp16; h0 -> slot 0; reset 128 WG flags
__global__ void lstm_prep(const float* __restrict__ x, const float* __restrict__ h0,
                          _Float16* __restrict__ xb, _Float16* __restrict__ hbuf,
                          unsigned* __restrict__ flags)
{
  size_t gid = (size_t)blockIdx.x * blockDim.x + threadIdx.x;
  size_t stride = (size_t)gridDim.x * blockDim.x;
  const size_t NX = (size_t)NBATCH * TSTEPS * DIN;
  for (size_t i = gid * 4; i < NX; i += stride * 4) {
    float4 v = *(const float4*)(x + i);
    xb[i + 0] = (_Float16)v.x;
    xb[i + 1] = (_Float16)v.y;
    xb[i + 2] = (_Float16)v.z;
    xb[i + 3] = (_Float16)v.w;
  }
  for (size_t i = gid; i < (size_t)HSLOT; i += stride)
    hbuf[i] = (_Float16)h0[i];
  if (gid < SCAN_WGS) flags[gid] = 0u;
}

__global__ __launch_bounds__(256, 1) void lstm_scan(
    const _Float16* __restrict__ xb,   // [N][T][D] fp16
    const float* __restrict__ Wx,      // [D][4H]
    const float* __restrict__ Wh,      // [H][4H]
    const float* __restrict__ bias,    // [4H]
    _Float16* __restrict__ hbuf,       // [2][N][H] fp16 ping-pong
    float* __restrict__ out,           // [N][T][H] fp32
    unsigned* __restrict__ flags)      // [128] per-WG step counters
{
  // fragment-linear weights: WF[ks][lane] = 16B B-fragment for K-slice ks
  __shared__ half8 WxF[16][64];        // 16 KB
  __shared__ half8 WhF[16][64];        // 16 KB

  const int wg   = blockIdx.x;         // owns hidden units wg*4..wg*4+3
  const int tid  = threadIdx.x;
  const int lane = tid & 63;
  const int wave = tid >> 6;           // m-slice: batch rows wave*16..+15

  // ---- one-time: stage weight slices fp32->fp16 into LDS (fragment order)
  {
    const int gate = tid & 3;
    const int k0   = tid >> 2;         // 0..63
    _Float16* wx = (_Float16*)WxF;
    _Float16* wh = (_Float16*)WhF;
    for (int pass = 0; pass < 8; ++pass) {
      int k = k0 + pass * 64;
      float4 vx = *(const float4*)(Wx + (size_t)k * NCOL + gate * 512 + wg * 4);
      float4 vh = *(const float4*)(Wh + (size_t)k * NCOL + gate * 512 + wg * 4);
      int base = (k >> 5) * 512 + (((k >> 3) & 3) * 16 + gate * 4) * 8 + (k & 7);
      wx[base + 0 * 8] = (_Float16)vx.x;
      wx[base + 1 * 8] = (_Float16)vx.y;
      wx[base + 2 * 8] = (_Float16)vx.z;
      wx[base + 3 * 8] = (_Float16)vx.w;
      wh[base + 0 * 8] = (_Float16)vh.x;
      wh[base + 1 * 8] = (_Float16)vh.y;
      wh[base + 2 * 8] = (_Float16)vh.z;
      wh[base + 3 * 8] = (_Float16)vh.w;
    }
  }
  __syncthreads();

  // MFMA 16x16x32 fragment indices (A: row=lane&15, k=(lane>>4)*8+j;
  //  D: col=lane&15, row=(lane>>4)*4+j)
  const int fr = lane & 15;
  const int q  = lane >> 4;
  const int fk = q * 8;
  const int mrow = wave * 16 + fr;     // batch row of this lane's A-fragment

  // per-lane bias for gate column fr: gate g=fr>>2, hidden hj=fr&3
  const float bias_fr = bias[(fr >> 2) * 512 + wg * 4 + (fr & 3)];

  // writer identity: lane publishes cell (nw, colw), j_w = fr>>2
  const int jw   = fr >> 2;
  const int nw   = wave * 16 + q * 4 + jw;
  const int colw = wg * 4 + (fr & 3);

  // cell state for rows q*4+j (j=0..3), hidden unit fr&3 (replicated over g)
  float c0 = 0.f, c1 = 0.f, c2 = 0.f, c3 = 0.f;

  // preload x fragments for t=0
  half8 xa[16];
#pragma unroll
  for (int ks = 0; ks < 16; ++ks)
    xa[ks] = *(const half8*)(xb + ((size_t)mrow * TSTEPS + 0) * DIN + ks * 32 + fk);

  const unsigned long long* flag64 = (const unsigned long long*)flags;

  for (int t = 0; t < TSTEPS; ++t) {
    // ---- discovery: wave 0 polls all 128 WG flags, broadcast via barrier
    if (t) {
      if (tid < 64) {
        for (;;) {
          unsigned long long v = __hip_atomic_load(
              flag64 + tid, __ATOMIC_RELAXED, __HIP_MEMORY_SCOPE_AGENT);
          bool pok = ((unsigned)v >= (unsigned)t) &&
                     ((unsigned)(v >> 32) >= (unsigned)t);
          if (__all(pok)) break;
          __builtin_amdgcn_s_sleep(2);
        }
      }
      __syncthreads();
    }

    // ---- x-MFMA phase first (xa regs die here; keeps pressure low) ----
    f32x4 a0 = {0.f, 0.f, 0.f, 0.f};
    f32x4 a1 = {0.f, 0.f, 0.f, 0.f};
    f32x4 a2 = {0.f, 0.f, 0.f, 0.f};
    f32x4 a3 = {0.f, 0.f, 0.f, 0.f};
#pragma unroll
    for (int ks = 0; ks < 16; ks += 4) {
      a0 = __builtin_amdgcn_mfma_f32_16x16x32_f16(xa[ks],     WxF[ks][lane],     a0, 0, 0, 0);
      a1 = __builtin_amdgcn_mfma_f32_16x16x32_f16(xa[ks + 1], WxF[ks + 1][lane], a1, 0, 0, 0);
      a2 = __builtin_amdgcn_mfma_f32_16x16x32_f16(xa[ks + 2], WxF[ks + 2][lane], a2, 0, 0, 0);
      a3 = __builtin_amdgcn_mfma_f32_16x16x32_f16(xa[ks + 3], WxF[ks + 3][lane], a3, 0, 0, 0);
    }

    // ---- h transport: 16 pipelined dwordx4 sc1 + waitcnt, ONE asm block ----
    // lane's h-frag ks: row mrow, fp16 cols ks*32 + q*8 .. +7
    // base = &h[mrow][q*8]; frag ks at byte offset ks*64
    {
      const _Float16* hbase = hbuf + (size_t)(t & 1) * HSLOT +
                              (size_t)mrow * HID + q * 8;
      u32x4 v0, v1, v2, v3, v4, v5, v6, v7, v8, v9, va, vb, vc, vd, ve, vf;
      asm volatile(
        "global_load_dwordx4 %0, %16, off sc1\n\t"
        "global_load_dwordx4 %1, %16, off offset:64 sc1\n\t"
        "global_load_dwordx4 %2, %16, off offset:128 sc1\n\t"
        "global_load_dwordx4 %3, %16, off offset:192 sc1\n\t"
        "global_load_dwordx4 %4, %16, off offset:256 sc1\n\t"
        "global_load_dwordx4 %5, %16, off offset:320 sc1\n\t"
        "global_load_dwordx4 %6, %16, off offset:384 sc1\n\t"
        "global_load_dwordx4 %7, %16, off offset:448 sc1\n\t"
        "global_load_dwordx4 %8, %16, off offset:512 sc1\n\t"
        "global_load_dwordx4 %9, %16, off offset:576 sc1\n\t"
        "global_load_dwordx4 %10, %16, off offset:640 sc1\n\t"
        "global_load_dwordx4 %11, %16, off offset:704 sc1\n\t"
        "global_load_dwordx4 %12, %16, off offset:768 sc1\n\t"
        "global_load_dwordx4 %13, %16, off offset:832 sc1\n\t"
        "global_load_dwordx4 %14, %16, off offset:896 sc1\n\t"
        "global_load_dwordx4 %15, %16, off offset:960 sc1\n\t"
        "s_waitcnt vmcnt(0)"
        : "=&v"(v0), "=&v"(v1), "=&v"(v2), "=&v"(v3),
          "=&v"(v4), "=&v"(v5), "=&v"(v6), "=&v"(v7),
          "=&v"(v8), "=&v"(v9), "=&v"(va), "=&v"(vb),
          "=&v"(vc), "=&v"(vd), "=&v"(ve), "=&v"(vf)
        : "v"(hbase)
        : "memory");

      // ---- h-MFMA phase ----
#define HMFMA(KS, ACC, V) \
      ACC = __builtin_amdgcn_mfma_f32_16x16x32_f16( \
          __builtin_bit_cast(half8, V), WhF[KS][lane], ACC, 0, 0, 0);
      HMFMA(0,  a0, v0) HMFMA(1,  a1, v1) HMFMA(2,  a2, v2) HMFMA(3,  a3, v3)
      HMFMA(4,  a0, v4) HMFMA(5,  a1, v5) HMFMA(6,  a2, v6) HMFMA(7,  a3, v7)
      HMFMA(8,  a0, v8) HMFMA(9,  a1, v9) HMFMA(10, a2, va) HMFMA(11, a3, vb)
      HMFMA(12, a0, vc) HMFMA(13, a1, vd) HMFMA(14, a2, ve) HMFMA(15, a3, vf)
#undef HMFMA
    }
    f32x4 acc = (a0 + a1) + (a2 + a3);

    // ---- in-register LSTM cell (gates exchanged via shfl_xor 4/8) ----
    float h0v, h1v, h2v, h3v;
#define LSTM_CELL(J, CJ, HJ)                                                  \
    {                                                                         \
      float av = acc[J] + bias_fr;                                            \
      float v4 = __shfl_xor(av, 4);                                           \
      float alo = (fr & 4) ? v4 : av;                                         \
      float ahi = (fr & 4) ? av : v4;                                         \
      float blo = __shfl_xor(alo, 8);                                         \
      float bhi = __shfl_xor(ahi, 8);                                         \
      float iv = (fr & 8) ? blo : alo;   /* gate 0: i */                      \
      float fv = (fr & 8) ? bhi : ahi;   /* gate 1: f */                      \
      float ov = (fr & 8) ? alo : blo;   /* gate 2: o */                      \
      float gv = (fr & 8) ? ahi : bhi;   /* gate 3: g */                      \
      float ig = fast_sigmoid(iv);                                            \
      float fg = fast_sigmoid(fv);                                            \
      float og = fast_sigmoid(ov);                                            \
      float gg = fast_tanh(gv);                                               \
      CJ = fg * CJ + ig * gg;                                                 \
      HJ = og * fast_tanh(CJ);                                                \
    }
    LSTM_CELL(0, c0, h0v)
    LSTM_CELL(1, c1, h1v)
    LSTM_CELL(2, c2, h2v)
    LSTM_CELL(3, c3, h3v)
#undef LSTM_CELL

    // writer value: j == jw (static-select, keeps arrays out of scratch)
    float hsel = (jw == 0) ? h0v : (jw == 1) ? h1v : (jw == 2) ? h2v : h3v;

    // ---- publish h (paired u32, agent store) + out (plain fp32) ----
    {
      float hpart = __shfl_xor(hsel, 1);
      if ((fr & 1) == 0) {
        _Float16 lo = (_Float16)hsel, hi = (_Float16)hpart;
        unsigned packed = (unsigned)__builtin_bit_cast(unsigned short, lo) |
                          ((unsigned)__builtin_bit_cast(unsigned short, hi) << 16);
        unsigned* hdst = (unsigned*)(hbuf + (size_t)((t + 1) & 1) * HSLOT +
                                     (size_t)nw * HID + colw);
        __hip_atomic_store(hdst, packed, __ATOMIC_RELAXED, __HIP_MEMORY_SCOPE_AGENT);
      }
    }
    out[((size_t)nw * TSTEPS + t) * HID + colw] = hsel;

    // ---- ack: all waves' h stores at coherence point, then WG flag ----
    asm volatile("s_waitcnt vmcnt(0)" ::: "memory");
    __syncthreads();
    if (tid == 0)
      __hip_atomic_store(&flags[wg], (unsigned)(t + 1),
                         __ATOMIC_RELAXED, __HIP_MEMORY_SCOPE_AGENT);

    // ---- prefetch x for t+1 (lands during next poll window) ----
    if (t + 1 < TSTEPS) {
#pragma unroll
      for (int ks = 0; ks < 16; ++ks)
        xa[ks] = *(const half8*)(xb + ((size_t)mrow * TSTEPS + (t + 1)) * DIN + ks * 32 + fk);
    }
  }
}

extern "C" void kernel_launch(void* const* d_in, const int* in_sizes, int n_in,
                              void* d_out, int out_size, void* d_ws, size_t ws_size,
                              hipStream_t stream) {
  const float* x  = (const float*)d_in[0];
  const float* h0 = (const float*)d_in[1];
  const float* Wx = (const float*)d_in[2];
  const float* Wh = (const float*)d_in[3];
  const float* b  = (const float*)d_in[4];
  float* out = (float*)d_out;

  char* ws = (char*)d_ws;
  _Float16* xb    = (_Float16*)ws;                           // 33,554,432 B
  _Float16* hbuf  = (_Float16*)(ws + 33554432);              //    262,144 B
  unsigned* flags = (unsigned*)(ws + 33554432 + 262144);     //        512 B

  lstm_prep<<<dim3(2048), dim3(256), 0, stream>>>(x, h0, xb, hbuf, flags);
  lstm_scan<<<dim3(SCAN_WGS), dim3(256), 0, stream>>>(xb, Wx, Wh, b, hbuf, out, flags);
}

// Round 10
// 2951.550 us; speedup vs baseline: 2.9640x; 1.0195x over previous
//
#include <hip/hip_runtime.h>
#include <cstddef>

// LSTM: N=64, T=512, D=512, H=512.
// gates[t] = [x_t | h_{t-1}] @ [Wx; Wh] + b  (K=1024, fp16 MFMA, fp32 accum)
// Persistent scan: 128 WGs x 256 thr, each WG owns 4 hidden units.
// R10 = R9 + restored R2 load/compute overlap + IC hot-line fixes:
//  - h transport: issue asm block (16 dwordx4 sc1, no wait) BEFORE x-MFMA,
//    wait asm AFTER x-MFMA with all 16 values as tied "+v" operands
//  - flags padded 1-per-128B-line (no store/poll line sharing)
//  - h publish packed to one u64 store per row (half the IC transactions)

typedef _Float16 half8 __attribute__((ext_vector_type(8)));
typedef float f32x4 __attribute__((ext_vector_type(4)));
typedef unsigned u32x4 __attribute__((ext_vector_type(4)));

#define NBATCH 64
#define TSTEPS 512
#define DIN    512
#define HID    512
#define NCOL   2048
#define SCAN_WGS 128
#define HSLOT  (NBATCH * HID)   // fp16 elements per ping-pong slot
#define FPAD   32               // u32 per flag slot (128B line)

__device__ __forceinline__ float fast_sigmoid(float x) {
  return 1.0f / (1.0f + __expf(-x));
}
__device__ __forceinline__ float fast_tanh(float x) {
  return 1.0f - 2.0f / (__expf(2.0f * x) + 1.0f);
}

// one-time per launch: x -> fp16; h0 -> slot 0; zero padded flag array
__global__ void lstm_prep(const float* __restrict__ x, const float* __restrict__ h0,
                          _Float16* __restrict__ xb, _Float16* __restrict__ hbuf,
                          unsigned* __restrict__ flags)
{
  size_t gid = (size_t)blockIdx.x * blockDim.x + threadIdx.x;
  size_t stride = (size_t)gridDim.x * blockDim.x;
  const size_t NX = (size_t)NBATCH * TSTEPS * DIN;
  for (size_t i = gid * 4; i < NX; i += stride * 4) {
    float4 v = *(const float4*)(x + i);
    xb[i + 0] = (_Float16)v.x;
    xb[i + 1] = (_Float16)v.y;
    xb[i + 2] = (_Float16)v.z;
    xb[i + 3] = (_Float16)v.w;
  }
  for (size_t i = gid; i < (size_t)HSLOT; i += stride)
    hbuf[i] = (_Float16)h0[i];
  if (gid < SCAN_WGS * FPAD) flags[gid] = 0u;
}

__global__ __launch_bounds__(256, 1) void lstm_scan(
    const _Float16* __restrict__ xb,   // [N][T][D] fp16
    const float* __restrict__ Wx,      // [D][4H]
    const float* __restrict__ Wh,      // [H][4H]
    const float* __restrict__ bias,    // [4H]
    _Float16* __restrict__ hbuf,       // [2][N][H] fp16 ping-pong
    float* __restrict__ out,           // [N][T][H] fp32
    unsigned* __restrict__ flags)      // [128*FPAD] padded WG step counters
{
  // fragment-linear weights: WF[ks][lane] = 16B B-fragment for K-slice ks
  __shared__ half8 WxF[16][64];        // 16 KB
  __shared__ half8 WhF[16][64];        // 16 KB

  const int wg   = blockIdx.x;         // owns hidden units wg*4..wg*4+3
  const int tid  = threadIdx.x;
  const int lane = tid & 63;
  const int wave = tid >> 6;           // m-slice: batch rows wave*16..+15

  // ---- one-time: stage weight slices fp32->fp16 into LDS (fragment order)
  {
    const int gate = tid & 3;
    const int k0   = tid >> 2;         // 0..63
    _Float16* wx = (_Float16*)WxF;
    _Float16* wh = (_Float16*)WhF;
    for (int pass = 0; pass < 8; ++pass) {
      int k = k0 + pass * 64;
      float4 vx = *(const float4*)(Wx + (size_t)k * NCOL + gate * 512 + wg * 4);
      float4 vh = *(const float4*)(Wh + (size_t)k * NCOL + gate * 512 + wg * 4);
      int base = (k >> 5) * 512 + (((k >> 3) & 3) * 16 + gate * 4) * 8 + (k & 7);
      wx[base + 0 * 8] = (_Float16)vx.x;
      wx[base + 1 * 8] = (_Float16)vx.y;
      wx[base + 2 * 8] = (_Float16)vx.z;
      wx[base + 3 * 8] = (_Float16)vx.w;
      wh[base + 0 * 8] = (_Float16)vh.x;
      wh[base + 1 * 8] = (_Float16)vh.y;
      wh[base + 2 * 8] = (_Float16)vh.z;
      wh[base + 3 * 8] = (_Float16)vh.w;
    }
  }
  __syncthreads();

  // MFMA 16x16x32 fragment indices (A: row=lane&15, k=(lane>>4)*8+j;
  //  D: col=lane&15, row=(lane>>4)*4+j)
  const int fr = lane & 15;
  const int q  = lane >> 4;
  const int fk = q * 8;
  const int mrow = wave * 16 + fr;     // batch row of this lane's A-fragment

  // per-lane bias for gate column fr: gate g=fr>>2, hidden hj=fr&3
  const float bias_fr = bias[(fr >> 2) * 512 + wg * 4 + (fr & 3)];

  // writer identity: lane publishes cell (nw, colw), j_w = fr>>2
  const int jw   = fr >> 2;
  const int nw   = wave * 16 + q * 4 + jw;
  const int colw = wg * 4 + (fr & 3);

  // cell state for rows q*4+j (j=0..3), hidden unit fr&3 (replicated over g)
  float c0 = 0.f, c1 = 0.f, c2 = 0.f, c3 = 0.f;

  // preload x fragments for t=0
  half8 xa[16];
#pragma unroll
  for (int ks = 0; ks < 16; ++ks)
    xa[ks] = *(const half8*)(xb + ((size_t)mrow * TSTEPS + 0) * DIN + ks * 32 + fk);

  for (int t = 0; t < TSTEPS; ++t) {
    // ---- discovery: wave 0 polls padded flags (2 lines per lane) ----
    if (t) {
      if (tid < 64) {
        const unsigned* f0 = flags + (size_t)lane * FPAD;
        const unsigned* f1 = flags + (size_t)(lane + 64) * FPAD;
        for (;;) {
          unsigned a = __hip_atomic_load(f0, __ATOMIC_RELAXED, __HIP_MEMORY_SCOPE_AGENT);
          unsigned b = __hip_atomic_load(f1, __ATOMIC_RELAXED, __HIP_MEMORY_SCOPE_AGENT);
          bool pok = (a >= (unsigned)t) && (b >= (unsigned)t);
          if (__all(pok)) break;
          __builtin_amdgcn_s_sleep(1);
        }
      }
      __syncthreads();
    }

    // ---- issue h loads early: ONE asm block, 16 dwordx4 sc1, NO wait ----
    u32x4 v0, v1, v2, v3, v4, v5, v6, v7, v8, v9, va, vb, vc, vd, ve, vf;
    {
      const _Float16* hbase = hbuf + (size_t)(t & 1) * HSLOT +
                              (size_t)mrow * HID + q * 8;
      asm volatile(
        "global_load_dwordx4 %0, %16, off sc1\n\t"
        "global_load_dwordx4 %1, %16, off offset:64 sc1\n\t"
        "global_load_dwordx4 %2, %16, off offset:128 sc1\n\t"
        "global_load_dwordx4 %3, %16, off offset:192 sc1\n\t"
        "global_load_dwordx4 %4, %16, off offset:256 sc1\n\t"
        "global_load_dwordx4 %5, %16, off offset:320 sc1\n\t"
        "global_load_dwordx4 %6, %16, off offset:384 sc1\n\t"
        "global_load_dwordx4 %7, %16, off offset:448 sc1\n\t"
        "global_load_dwordx4 %8, %16, off offset:512 sc1\n\t"
        "global_load_dwordx4 %9, %16, off offset:576 sc1\n\t"
        "global_load_dwordx4 %10, %16, off offset:640 sc1\n\t"
        "global_load_dwordx4 %11, %16, off offset:704 sc1\n\t"
        "global_load_dwordx4 %12, %16, off offset:768 sc1\n\t"
        "global_load_dwordx4 %13, %16, off offset:832 sc1\n\t"
        "global_load_dwordx4 %14, %16, off offset:896 sc1\n\t"
        "global_load_dwordx4 %15, %16, off offset:960 sc1"
        : "=&v"(v0), "=&v"(v1), "=&v"(v2), "=&v"(v3),
          "=&v"(v4), "=&v"(v5), "=&v"(v6), "=&v"(v7),
          "=&v"(v8), "=&v"(v9), "=&v"(va), "=&v"(vb),
          "=&v"(vc), "=&v"(vd), "=&v"(ve), "=&v"(vf)
        : "v"(hbase)
        : "memory");
    }

    // ---- x-MFMA phase (runs under the h-load flight) ----
    f32x4 a0 = {0.f, 0.f, 0.f, 0.f};
    f32x4 a1 = {0.f, 0.f, 0.f, 0.f};
    f32x4 a2 = {0.f, 0.f, 0.f, 0.f};
    f32x4 a3 = {0.f, 0.f, 0.f, 0.f};
#pragma unroll
    for (int ks = 0; ks < 16; ks += 4) {
      a0 = __builtin_amdgcn_mfma_f32_16x16x32_f16(xa[ks],     WxF[ks][lane],     a0, 0, 0, 0);
      a1 = __builtin_amdgcn_mfma_f32_16x16x32_f16(xa[ks + 1], WxF[ks + 1][lane], a1, 0, 0, 0);
      a2 = __builtin_amdgcn_mfma_f32_16x16x32_f16(xa[ks + 2], WxF[ks + 2][lane], a2, 0, 0, 0);
      a3 = __builtin_amdgcn_mfma_f32_16x16x32_f16(xa[ks + 3], WxF[ks + 3][lane], a3, 0, 0, 0);
    }

    // ---- wait: tied operands keep the 16 values pinned across the wait ----
    asm volatile("s_waitcnt vmcnt(0)"
        : "+v"(v0), "+v"(v1), "+v"(v2), "+v"(v3),
          "+v"(v4), "+v"(v5), "+v"(v6), "+v"(v7),
          "+v"(v8), "+v"(v9), "+v"(va), "+v"(vb),
          "+v"(vc), "+v"(vd), "+v"(ve), "+v"(vf)
        :: "memory");
    __builtin_amdgcn_sched_barrier(0);

    // ---- h-MFMA phase ----
#define HMFMA(KS, ACC, V) \
    ACC = __builtin_amdgcn_mfma_f32_16x16x32_f16( \
        __builtin_bit_cast(half8, V), WhF[KS][lane], ACC, 0, 0, 0);
    HMFMA(0,  a0, v0) HMFMA(1,  a1, v1) HMFMA(2,  a2, v2) HMFMA(3,  a3, v3)
    HMFMA(4,  a0, v4) HMFMA(5,  a1, v5) HMFMA(6,  a2, v6) HMFMA(7,  a3, v7)
    HMFMA(8,  a0, v8) HMFMA(9,  a1, v9) HMFMA(10, a2, va) HMFMA(11, a3, vb)
    HMFMA(12, a0, vc) HMFMA(13, a1, vd) HMFMA(14, a2, ve) HMFMA(15, a3, vf)
#undef HMFMA
    f32x4 acc = (a0 + a1) + (a2 + a3);

    // ---- in-register LSTM cell (gates exchanged via shfl_xor 4/8) ----
    float h0v, h1v, h2v, h3v;
#define LSTM_CELL(J, CJ, HJ)                                                  \
    {                                                                         \
      float av = acc[J] + bias_fr;                                            \
      float v4 = __shfl_xor(av, 4);                                           \
      float alo = (fr & 4) ? v4 : av;                                         \
      float ahi = (fr & 4) ? av : v4;                                         \
      float blo = __shfl_xor(alo, 8);                                         \
      float bhi = __shfl_xor(ahi, 8);                                         \
      float iv = (fr & 8) ? blo : alo;   /* gate 0: i */                      \
      float fv = (fr & 8) ? bhi : ahi;   /* gate 1: f */                      \
      float ov = (fr & 8) ? alo : blo;   /* gate 2: o */                      \
      float gv = (fr & 8) ? ahi : bhi;   /* gate 3: g */                      \
      float ig = fast_sigmoid(iv);                                            \
      float fg = fast_sigmoid(fv);                                            \
      float og = fast_sigmoid(ov);                                            \
      float gg = fast_tanh(gv);                                               \
      CJ = fg * CJ + ig * gg;                                                 \
      HJ = og * fast_tanh(CJ);                                                \
    }
    LSTM_CELL(0, c0, h0v)
    LSTM_CELL(1, c1, h1v)
    LSTM_CELL(2, c2, h2v)
    LSTM_CELL(3, c3, h3v)
#undef LSTM_CELL

    // writer value: j == jw (static-select, keeps arrays out of scratch)
    float hsel = (jw == 0) ? h0v : (jw == 1) ? h1v : (jw == 2) ? h2v : h3v;

    // ---- publish h: pack 4 cols (8B) per row, one u64 store per row ----
    {
      float hp1 = __shfl_xor(hsel, 1);            // col ^1
      _Float16 e0 = (_Float16)hsel, e1 = (_Float16)hp1;
      unsigned pair = (unsigned)__builtin_bit_cast(unsigned short, e0) |
                      ((unsigned)__builtin_bit_cast(unsigned short, e1) << 16);
      // gather pair from fr^2 (cols 2,3) into fr&3==0 lane
      unsigned other = __builtin_bit_cast(unsigned,
          __shfl_xor(__builtin_bit_cast(float, pair), 2));
      if ((fr & 3) == 0) {
        unsigned long long w = (unsigned long long)pair |
                               ((unsigned long long)other << 32);
        unsigned long long* hdst = (unsigned long long*)
            (hbuf + (size_t)((t + 1) & 1) * HSLOT + (size_t)nw * HID + wg * 4);
        __hip_atomic_store(hdst, w, __ATOMIC_RELAXED, __HIP_MEMORY_SCOPE_AGENT);
      }
    }
    out[((size_t)nw * TSTEPS + t) * HID + colw] = hsel;

    // ---- ack: all waves' h stores at coherence point, then WG flag ----
    asm volatile("s_waitcnt vmcnt(0)" ::: "memory");
    __syncthreads();
    if (tid == 0)
      __hip_atomic_store(&flags[(size_t)wg * FPAD], (unsigned)(t + 1),
                         __ATOMIC_RELAXED, __HIP_MEMORY_SCOPE_AGENT);

    // ---- prefetch x for t+1 (lands during next poll window) ----
    if (t + 1 < TSTEPS) {
#pragma unroll
      for (int ks = 0; ks < 16; ++ks)
        xa[ks] = *(const half8*)(xb + ((size_t)mrow * TSTEPS + (t + 1)) * DIN + ks * 32 + fk);
    }
  }
}

extern "C" void kernel_launch(void* const* d_in, const int* in_sizes, int n_in,
                              void* d_out, int out_size, void* d_ws, size_t ws_size,
                              hipStream_t stream) {
  const float* x  = (const float*)d_in[0];
  const float* h0 = (const float*)d_in[1];
  const float* Wx = (const float*)d_in[2];
  const float* Wh = (const float*)d_in[3];
  const float* b  = (const float*)d_in[4];
  float* out = (float*)d_out;

  char* ws = (char*)d_ws;
  _Float16* xb    = (_Float16*)ws;                           // 33,554,432 B
  _Float16* hbuf  = (_Float16*)(ws + 33554432);              //    262,144 B
  unsigned* flags = (unsigned*)(ws + 33554432 + 262144);     //     16,384 B

  lstm_prep<<<dim3(2048), dim3(256), 0, stream>>>(x, h0, xb, hbuf, flags);
  lstm_scan<<<dim3(SCAN_WGS), dim3(256), 0, stream>>>(xb, Wx, Wh, b, hbuf, out, flags);
}